// Round 3
// baseline (281.101 us; speedup 1.0000x reference)
//
#include <hip/hip_runtime.h>
#include <math.h>
#include <float.h>

#define D_DIM 768
#define K_C   256
#define KC    32
#define NCH   24
#define BMR   128
#define BPAD  40
#define MAXFIX 32768
#define MARGIN 2e-2f

typedef __attribute__((ext_vector_type(8))) short s16x8;
typedef __attribute__((ext_vector_type(4))) float f32x4;

__device__ inline unsigned short f2bf(float x) {      // RNE f32 -> bf16 bits
    unsigned u = __float_as_uint(x);
    unsigned r = 0x7FFFu + ((u >> 16) & 1u);
    return (unsigned short)((u + r) >> 16);
}
__device__ inline float bf2f(unsigned short h) {
    return __uint_as_float(((unsigned)h) << 16);
}
__device__ inline unsigned pk_trunc(float a, float b) { // 2 f32 -> 2 bf16 (trunc)
    return (__float_as_uint(a) >> 16) | (__float_as_uint(b) & 0xFFFF0000u);
}

// ---------------- prep: C -> chunk-major bf16 hi/lo (RNE), c2 in f64 ----------------
__global__ __launch_bounds__(256) void kprep(const float* __restrict__ C,
    short* __restrict__ Chik, short* __restrict__ Clok,
    float* __restrict__ c2f, int* __restrict__ fix_cnt)
{
    const int k = blockIdx.x;      // centroid
    const int t = threadIdx.x;
    __shared__ double red[4];
    double s = 0.0;
    for (int d = t; d < D_DIM; d += 256) {
        float x = C[(size_t)k*D_DIM + d];
        unsigned short h = f2bf(x);
        unsigned short l = f2bf(x - bf2f(h));
        int ch = d >> 5, kk = d & 31;
        size_t o = ((size_t)ch*K_C + k)*KC + kk;
        Chik[o] = (short)h;
        Clok[o] = (short)l;
        s += (double)x * (double)x;
    }
#pragma unroll
    for (int m = 1; m < 64; m <<= 1) s += __shfl_xor(s, m, 64);
    if ((t & 63) == 0) red[t >> 6] = s;
    __syncthreads();
    if (t == 0) {
        c2f[k] = (float)(red[0] + red[1] + red[2] + red[3]);
        if (k == 0) *fix_cnt = 0;
    }
}

// ---------------- main fused MFMA kernel (128 rows x 128 cols per block) ----------------
__global__ __launch_bounds__(256, 4) void kdist(const float* __restrict__ E,
    const short* __restrict__ Chik, const short* __restrict__ Clok,
    const float* __restrict__ c2f, float* __restrict__ partials,
    float4* __restrict__ blocktop)
{
    __shared__ short EhiL[BMR*BPAD];          // 10 KB
    __shared__ short ChiL[128*BPAD];          // 10 KB
    __shared__ short CloL[128*BPAD];          // 10 KB
    __shared__ float e2s[BMR];
    __shared__ float spart[2][128][3];
    __shared__ float4 topb[2][128];

    const int t    = threadIdx.x;
    const int lane = t & 63;
    const int w    = t >> 6;
    const int wm   = w >> 1, wq = w & 1;      // wave row-half / col-quarter
    const int c4   = lane & 15, sgr = lane >> 4;
    const int bid  = blockIdx.x;
    const int R0   = (bid >> 1) * BMR;
    const int C0   = (bid & 1) * 128;

    f32x4 acc[4][4];
#pragma unroll
    for (int m = 0; m < 4; ++m)
#pragma unroll
        for (int n = 0; n < 4; ++n) acc[m][n] = (f32x4){0.f,0.f,0.f,0.f};

    const int rw = t >> 1, sg = t & 1;
    const float* Ep = E + (size_t)(R0 + rw)*D_DIM + sg*16;
    unsigned* Edst = (unsigned*)&EhiL[rw*BPAD + sg*16];
    const short* Chp = Chik + ((size_t)(C0 + rw))*KC + sg*16;
    const short* Clp = Clok + ((size_t)(C0 + rw))*KC + sg*16;
    s16x8* Chd = (s16x8*)&ChiL[rw*BPAD + sg*16];
    s16x8* Cld = (s16x8*)&CloL[rw*BPAD + sg*16];

    float e2p = 0.f;

    for (int ch = 0; ch < NCH; ++ch) {
        __syncthreads();
        const size_t co = (size_t)ch * K_C * KC;
        // C stage (pre-converted hi/lo, coalesced 16B loads)
        s16x8 h0 = *reinterpret_cast<const s16x8*>(Chp + co);
        s16x8 h1 = *reinterpret_cast<const s16x8*>(Chp + co + 8);
        s16x8 l0 = *reinterpret_cast<const s16x8*>(Clp + co);
        s16x8 l1 = *reinterpret_cast<const s16x8*>(Clp + co + 8);
        // E stage: 16 f32 -> bf16-hi (trunc), accumulate e2 in f32
        const float* ep = Ep + ch*KC;
        float4 v0 = *reinterpret_cast<const float4*>(ep);
        float4 v1 = *reinterpret_cast<const float4*>(ep + 4);
        float4 v2 = *reinterpret_cast<const float4*>(ep + 8);
        float4 v3 = *reinterpret_cast<const float4*>(ep + 12);
        e2p = fmaf(v0.x,v0.x,e2p); e2p = fmaf(v0.y,v0.y,e2p);
        e2p = fmaf(v0.z,v0.z,e2p); e2p = fmaf(v0.w,v0.w,e2p);
        e2p = fmaf(v1.x,v1.x,e2p); e2p = fmaf(v1.y,v1.y,e2p);
        e2p = fmaf(v1.z,v1.z,e2p); e2p = fmaf(v1.w,v1.w,e2p);
        e2p = fmaf(v2.x,v2.x,e2p); e2p = fmaf(v2.y,v2.y,e2p);
        e2p = fmaf(v2.z,v2.z,e2p); e2p = fmaf(v2.w,v2.w,e2p);
        e2p = fmaf(v3.x,v3.x,e2p); e2p = fmaf(v3.y,v3.y,e2p);
        e2p = fmaf(v3.z,v3.z,e2p); e2p = fmaf(v3.w,v3.w,e2p);
        uint4 pA, pB;
        pA.x = pk_trunc(v0.x, v0.y); pA.y = pk_trunc(v0.z, v0.w);
        pA.z = pk_trunc(v1.x, v1.y); pA.w = pk_trunc(v1.z, v1.w);
        pB.x = pk_trunc(v2.x, v2.y); pB.y = pk_trunc(v2.z, v2.w);
        pB.z = pk_trunc(v3.x, v3.y); pB.w = pk_trunc(v3.z, v3.w);
        Chd[0] = h0; Chd[1] = h1;
        Cld[0] = l0; Cld[1] = l1;
        reinterpret_cast<uint4*>(Edst)[0] = pA;
        reinterpret_cast<uint4*>(Edst)[1] = pB;
        __syncthreads();

        // ---- MFMA: acc += Ehi*Chi + Ehi*Clo ----
        const int ks = sgr * 8;
        s16x8 ah[4];
#pragma unroll
        for (int m = 0; m < 4; ++m)
            ah[m] = *reinterpret_cast<const s16x8*>(&EhiL[(wm*64 + m*16 + c4)*BPAD + ks]);
#pragma unroll
        for (int n = 0; n < 4; ++n) {
            const int cr = (wq*64 + n*16 + c4)*BPAD + ks;
            s16x8 bh = *reinterpret_cast<const s16x8*>(&ChiL[cr]);
            s16x8 bl = *reinterpret_cast<const s16x8*>(&CloL[cr]);
#pragma unroll
            for (int m = 0; m < 4; ++m)
                acc[m][n] = __builtin_amdgcn_mfma_f32_16x16x32_bf16(ah[m], bh, acc[m][n], 0, 0, 0);
#pragma unroll
            for (int m = 0; m < 4; ++m)
                acc[m][n] = __builtin_amdgcn_mfma_f32_16x16x32_bf16(ah[m], bl, acc[m][n], 0, 0, 0);
        }
    }

    // ---- finish e2 per row ----
    {
        float o = __shfl_xor(e2p, 1, 64);
        if ((t & 1) == 0) e2s[t >> 1] = e2p + o;
    }
    __syncthreads();

    float e2r[4][4];
#pragma unroll
    for (int m = 0; m < 4; ++m)
#pragma unroll
        for (int g = 0; g < 4; ++g)
            e2r[m][g] = e2s[wm*64 + m*16 + sgr*4 + g];
    float c2v[4];
#pragma unroll
    for (int n = 0; n < 4; ++n) c2v[n] = c2f[C0 + wq*64 + n*16 + c4];

    // ---- dot -> dist (C/D: col=lane&15, row=(lane>>4)*4+reg) ----
#pragma unroll
    for (int m = 0; m < 4; ++m)
#pragma unroll
        for (int n = 0; n < 4; ++n) {
            f32x4 v = acc[m][n];
#pragma unroll
            for (int g = 0; g < 4; ++g) {
                float d2 = fmaf(-2.f, v[g], e2r[m][g] + c2v[n]);
                v[g] = sqrtf(fmaxf(d2, 0.f));
            }
            acc[m][n] = v;
        }

    // ---- top-2 argmin per row over this wave's 64 cols ----
#pragma unroll
    for (int m = 0; m < 4; ++m)
#pragma unroll
        for (int g = 0; g < 4; ++g) {
            float v1 = FLT_MAX, v2 = FLT_MAX;
            int i1 = 0x7fffffff, i2 = 0x7fffffff;
#pragma unroll
            for (int n = 0; n < 4; ++n) {
                float d = acc[m][n][g];
                int idx = C0 + wq*64 + n*16 + c4;
                if (d < v1)      { v2 = v1; i2 = i1; v1 = d; i1 = idx; }
                else if (d < v2) { v2 = d; i2 = idx; }
            }
#pragma unroll
            for (int msk = 1; msk < 16; msk <<= 1) {
                float b1 = __shfl_xor(v1, msk, 64); int bi1 = __shfl_xor(i1, msk, 64);
                float b2 = __shfl_xor(v2, msk, 64); int bi2 = __shfl_xor(i2, msk, 64);
                bool afirst = (v1 < b1) || (v1 == b1 && i1 < bi1);
                float n1, n2; int ni1, ni2;
                if (afirst) {
                    n1 = v1; ni1 = i1;
                    bool s = (v2 < b1) || (v2 == b1 && i2 < bi1);
                    n2 = s ? v2 : b1; ni2 = s ? i2 : bi1;
                } else {
                    n1 = b1; ni1 = bi1;
                    bool s = (b2 < v1) || (b2 == v1 && bi2 < i1);
                    n2 = s ? b2 : v1; ni2 = s ? bi2 : i1;
                }
                v1 = n1; i1 = ni1; v2 = n2; i2 = ni2;
            }
            if (c4 == 0) {
                float4 r; r.x = v1; r.y = (float)i1; r.z = v2; r.w = (float)i2;
                topb[wq][wm*64 + m*16 + sgr*4 + g] = r;
            }
        }

    // ---- per-centroid softmin partials over this wave's 64 rows ----
#pragma unroll
    for (int n = 0; n < 4; ++n) {
        float m0 = FLT_MAX;
#pragma unroll
        for (int m = 0; m < 4; ++m)
#pragma unroll
            for (int g = 0; g < 4; ++g) m0 = fminf(m0, acc[m][n][g]);
        float s1 = 0.f, s2 = 0.f;
#pragma unroll
        for (int m = 0; m < 4; ++m)
#pragma unroll
            for (int g = 0; g < 4; ++g) {
                float d = acc[m][n][g];
                float e = expf(m0 - d);
                s1 += e; s2 = fmaf(d, e, s2);
            }
#pragma unroll
        for (int msk = 16; msk < 64; msk <<= 1) {
            float om = __shfl_xor(m0, msk, 64);
            float oa = __shfl_xor(s1, msk, 64);
            float ob = __shfl_xor(s2, msk, 64);
            float Mn = fminf(m0, om);
            float sa = expf(Mn - m0), sb = expf(Mn - om);
            s1 = s1*sa + oa*sb;
            s2 = s2*sa + ob*sb;
            m0 = Mn;
        }
        if (lane < 16) {
            int cc = wq*64 + n*16 + c4;
            spart[wm][cc][0] = m0; spart[wm][cc][1] = s1; spart[wm][cc][2] = s2;
        }
    }
    __syncthreads();

    if (t < 128) {
        // merge top-2 across the two col-quarters (a has lower indices)
        float4 a = topb[0][t], b = topb[1][t];
        float v1, v2; int i1, i2;
        if (a.x <= b.x) {
            v1 = a.x; i1 = (int)a.y;
            bool s = (a.z <= b.x);
            v2 = s ? a.z : b.x; i2 = s ? (int)a.w : (int)b.y;
        } else {
            v1 = b.x; i1 = (int)b.y;
            bool s = (a.x <= b.z);
            v2 = s ? a.x : b.z; i2 = s ? (int)a.y : (int)b.w;
        }
        float4 r; r.x = v1; r.y = (float)i1; r.z = v2; r.w = (float)i2;
        blocktop[(size_t)bid*128 + t] = r;
        // merge softmin partials across row-halves
        float M = spart[0][t][0], A = spart[0][t][1], Bv = spart[0][t][2];
        float om = spart[1][t][0], oa = spart[1][t][1], ob = spart[1][t][2];
        float Mn = fminf(M, om);
        float sa = expf(Mn - M), sb = expf(Mn - om);
        A = A*sa + oa*sb; Bv = Bv*sa + ob*sb;
        float* p = &partials[((size_t)bid*128 + t)*3];
        p[0] = Mn; p[1] = A; p[2] = Bv;
    }
}

// ---------------- merge col-halves: labels + near-tie flags ----------------
__global__ __launch_bounds__(256) void kmerge(const float4* __restrict__ blocktop,
    float* __restrict__ labels, int* __restrict__ fix_cnt, int* __restrict__ fix_list)
{
    const int r = blockIdx.x*256 + threadIdx.x;
    const size_t base = (size_t)(r >> 7) * 256 + (r & 127);
    float4 a = blocktop[base];
    float4 b = blocktop[base + 128];
    float v1, v2; int i1, i2;
    if (a.x <= b.x) {
        v1 = a.x; i1 = (int)a.y;
        bool s = (a.z <= b.x);
        v2 = s ? a.z : b.x; i2 = s ? (int)a.w : (int)b.y;
    } else {
        v1 = b.x; i1 = (int)b.y;
        bool s = (a.x <= b.z);
        v2 = s ? a.x : b.z; i2 = s ? (int)a.y : (int)b.w;
    }
    labels[r] = (float)i1;
    if (v2 - v1 < MARGIN) {
        int slot = atomicAdd(fix_cnt, 1);
        if (slot < MAXFIX) {
            fix_list[slot*3+0] = r;
            fix_list[slot*3+1] = i1;
            fix_list[slot*3+2] = i2;
        }
    }
}

// ---------------- stage A refine: full f32 rescore of flagged rows -> top-2 ----------------
__global__ __launch_bounds__(256, 2) void krefA(const float* __restrict__ E,
    const float* __restrict__ C, const float* __restrict__ c2f,
    const int* __restrict__ fix_cnt, int* __restrict__ fix_list)
{
    __shared__ float CL[256][33];
    __shared__ float EL[16][33];
    __shared__ int   rids[16];
    __shared__ float4 wred[4];

    int cnt = *fix_cnt; if (cnt > MAXFIX) cnt = MAXFIX;
    const int base = blockIdx.x * 16;
    if (base >= cnt) return;
    const int nr = (cnt - base < 16) ? (cnt - base) : 16;
    const int t = threadIdx.x;
    const int lane = t & 63, w = t >> 6;

    if (t < 16) {
        int e = base + ((t < nr) ? t : 0);
        rids[t] = fix_list[e*3];
    }
    __syncthreads();

    float acc[16];
#pragma unroll
    for (int r = 0; r < 16; ++r) acc[r] = 0.f;

    for (int ch = 0; ch < NCH; ++ch) {
        const int ck = ch * KC;
        __syncthreads();
#pragma unroll
        for (int i = 0; i < 8; ++i) {              // stage C chunk [256][32]
            int idx = t + 256*i;
            int row = idx >> 3, d4 = (idx & 7) * 4;
            float4 v = *reinterpret_cast<const float4*>(&C[(size_t)row*D_DIM + ck + d4]);
            CL[row][d4+0] = v.x; CL[row][d4+1] = v.y;
            CL[row][d4+2] = v.z; CL[row][d4+3] = v.w;
        }
        if (t < 128) {                              // stage E rows [16][32]
            int row = t >> 3, d4 = (t & 7) * 4;
            float4 v = *reinterpret_cast<const float4*>(&E[(size_t)rids[row]*D_DIM + ck + d4]);
            EL[row][d4+0] = v.x; EL[row][d4+1] = v.y;
            EL[row][d4+2] = v.z; EL[row][d4+3] = v.w;
        }
        __syncthreads();
        for (int d = 0; d < KC; ++d) {
            float cv = CL[t][d];
#pragma unroll
            for (int r = 0; r < 16; ++r)
                acc[r] = fmaf(EL[r][d], cv, acc[r]);
        }
    }

    const float myc2 = c2f[t];
    for (int r = 0; r < nr; ++r) {
        float v1 = myc2 - 2.f*acc[r];              // monotone with dist
        float v2 = FLT_MAX;
        int i1 = t, i2 = 0x7fffffff;
#pragma unroll
        for (int msk = 1; msk < 64; msk <<= 1) {
            float b1 = __shfl_xor(v1, msk, 64); int bi1 = __shfl_xor(i1, msk, 64);
            float b2 = __shfl_xor(v2, msk, 64); int bi2 = __shfl_xor(i2, msk, 64);
            bool afirst = (v1 < b1) || (v1 == b1 && i1 < bi1);
            float n1, n2; int ni1, ni2;
            if (afirst) {
                n1 = v1; ni1 = i1;
                bool s = (v2 < b1) || (v2 == b1 && i2 < bi1);
                n2 = s ? v2 : b1; ni2 = s ? i2 : bi1;
            } else {
                n1 = b1; ni1 = bi1;
                bool s = (b2 < v1) || (b2 == v1 && bi2 < i1);
                n2 = s ? b2 : v1; ni2 = s ? bi2 : i1;
            }
            v1 = n1; i1 = ni1; v2 = n2; i2 = ni2;
        }
        if (lane == 0) { float4 q; q.x=v1; q.y=(float)i1; q.z=v2; q.w=(float)i2; wred[w]=q; }
        __syncthreads();
        if (t == 0) {
            float4 m = wred[0];
            float v1f = m.x, v2f = m.z; int i1f = (int)m.y, i2f = (int)m.w;
#pragma unroll
            for (int i = 1; i < 4; ++i) {
                float4 o = wred[i];
                float ov1 = o.x, ov2 = o.z; int oi1 = (int)o.y, oi2 = (int)o.w;
                bool afirst = (v1f < ov1) || (v1f == ov1 && i1f < oi1);
                if (afirst) {
                    bool s = (v2f < ov1) || (v2f == ov1 && i2f < oi1);
                    v2f = s ? v2f : ov1; i2f = s ? i2f : oi1;
                } else {
                    bool s = (ov2 < v1f) || (ov2 == v1f && oi2 < i1f);
                    float nv2 = s ? ov2 : v1f; int ni2 = s ? oi2 : i1f;
                    v1f = ov1; i1f = oi1; v2f = nv2; i2f = ni2;
                }
            }
            fix_list[(base+r)*3+1] = i1f;
            fix_list[(base+r)*3+2] = i2f;
        }
        __syncthreads();
    }
}

// ---------------- stage B refine: exact f64 compare of the top-2 ----------------
__global__ __launch_bounds__(256) void krefB(const float* __restrict__ E,
    const float* __restrict__ C, const int* __restrict__ fix_cnt,
    const int* __restrict__ fix_list, float* __restrict__ labels)
{
    int cnt = *fix_cnt; if (cnt > MAXFIX) cnt = MAXFIX;
    int lane = threadIdx.x & 63;
    int wv = (int)((blockIdx.x * blockDim.x + threadIdx.x) >> 6);
    const int NW = (gridDim.x * blockDim.x) >> 6;
    for (int e = wv; e < cnt; e += NW) {
        int row = fix_list[e*3+0], k1 = fix_list[e*3+1], k2 = fix_list[e*3+2];
        double d1 = 0, d2 = 0, q1 = 0, q2 = 0;
        for (int d = lane; d < D_DIM; d += 64) {
            double ed = (double)E[(size_t)row*D_DIM + d];
            double ca = (double)C[(size_t)k1*D_DIM + d];
            double cb = (double)C[(size_t)k2*D_DIM + d];
            d1 += ed*ca; q1 += ca*ca;
            d2 += ed*cb; q2 += cb*cb;
        }
#pragma unroll
        for (int msk = 32; msk; msk >>= 1) {
            d1 += __shfl_down(d1, msk, 64);
            d2 += __shfl_down(d2, msk, 64);
            q1 += __shfl_down(q1, msk, 64);
            q2 += __shfl_down(q2, msk, 64);
        }
        if (lane == 0) {
            double val1 = q1 - 2.0*d1, val2 = q2 - 2.0*d2;   // e2 cancels
            int lab = (val2 < val1 || (val2 == val1 && k2 < k1)) ? k2 : k1;
            labels[row] = (float)lab;
        }
    }
}

// ---------------- per-centroid global combine ----------------
__global__ __launch_bounds__(256) void kcol(const float* __restrict__ partials,
                                            float* __restrict__ colloss, int NBrow)
{
    __shared__ float Wm[4], Wa[4], Wb[4];
    const int c = blockIdx.x;
    const int half = c >> 7, lc = c & 127;
    const int t = threadIdx.x;
    float M = FLT_MAX, A = 0.f, Bv = 0.f;
    for (int b = t; b < NBrow; b += 256) {
        const float* p = &partials[(((size_t)b*2 + half)*128 + lc)*3];
        float om = p[0], oa = p[1], ob = p[2];
        float Mn = fminf(M, om);
        float sa = expf(Mn - M), sb = expf(Mn - om);
        A = A*sa + oa*sb; Bv = Bv*sa + ob*sb; M = Mn;
    }
    for (int msk = 1; msk < 64; msk <<= 1) {
        float om = __shfl_xor(M, msk, 64);
        float oa = __shfl_xor(A, msk, 64);
        float ob = __shfl_xor(Bv, msk, 64);
        float Mn = fminf(M, om);
        float sa = expf(Mn - M), sb = expf(Mn - om);
        A = A*sa + oa*sb; Bv = Bv*sa + ob*sb; M = Mn;
    }
    int lane = t & 63, wv = t >> 6;
    if (lane == 0) { Wm[wv] = M; Wa[wv] = A; Wb[wv] = Bv; }
    __syncthreads();
    if (t == 0) {
#pragma unroll
        for (int i = 1; i < 4; ++i) {
            float om = Wm[i], oa = Wa[i], ob = Wb[i];
            float Mn = fminf(M, om);
            float sa = expf(Mn - M), sb = expf(Mn - om);
            A = A*sa + oa*sb; Bv = Bv*sa + ob*sb; M = Mn;
        }
        colloss[c] = Bv / A;
    }
}

// ---------------- final mean over centroids ----------------
__global__ __launch_bounds__(256) void kfinal(const float* __restrict__ colloss,
                                              float* __restrict__ out)
{
    __shared__ float Ws[4];
    int t = threadIdx.x;
    float v = colloss[t];
    for (int msk = 1; msk < 64; msk <<= 1) v += __shfl_xor(v, msk, 64);
    if ((t & 63) == 0) Ws[t >> 6] = v;
    __syncthreads();
    if (t == 0) out[0] = (Ws[0] + Ws[1] + Ws[2] + Ws[3]) / 256.0f;
}

extern "C" void kernel_launch(void* const* d_in, const int* in_sizes, int n_in,
                              void* d_out, int out_size, void* d_ws, size_t ws_size,
                              hipStream_t stream)
{
    const float* E = (const float*)d_in[0];
    const float* C = (const float*)d_in[1];
    float* out = (float*)d_out;

    const int Bn    = in_sizes[0] / D_DIM;   // 65536
    const int NBrow = Bn / BMR;              // 512
    const int NB    = NBrow * 2;             // 1024 (col-split x2)

    char* ws = (char*)d_ws;
    float*  c2f      = (float*)ws;                                   // 1 KB
    int*    fix_cnt  = (int*)(ws + 1024);
    int*    fix_list = (int*)(ws + 1088);                            // MAXFIX*12
    short*  Chik     = (short*)(ws + 1088 + MAXFIX*12);              // 384 KB
    short*  Clok     = Chik + (size_t)NCH*K_C*KC;                    // 384 KB
    float*  partials = (float*)(Clok + (size_t)NCH*K_C*KC);          // NB*128*3*4
    float4* blocktop = (float4*)(partials + (size_t)NB*128*3);       // NB*128*16
    float*  colloss  = (float*)(blocktop + (size_t)NB*128);
    float*  labels   = out + 1;

    kprep <<<K_C, 256, 0, stream>>>(C, Chik, Clok, c2f, fix_cnt);
    kdist <<<NB,  256, 0, stream>>>(E, Chik, Clok, c2f, partials, blocktop);
    kmerge<<<Bn/256, 256, 0, stream>>>(blocktop, labels, fix_cnt, fix_list);
    krefA <<<MAXFIX/16, 256, 0, stream>>>(E, C, c2f, fix_cnt, fix_list);
    krefB <<<256, 256, 0, stream>>>(E, C, fix_cnt, fix_list, labels);
    kcol  <<<K_C, 256, 0, stream>>>(partials, colloss, NBrow);
    kfinal<<<1,   256, 0, stream>>>(colloss, out);
}

// Round 4
// 116.247 us; speedup vs baseline: 2.4181x; 2.4181x over previous
//
#include <hip/hip_runtime.h>
#include <math.h>
#include <float.h>

#define D_DIM 768
#define K_C   256
#define KC    32
#define NCH   24
#define BMR   128
#define MAXFIX 32768
#define MARGIN 1e-3f

typedef __attribute__((ext_vector_type(8))) short s16x8;
typedef __attribute__((ext_vector_type(4))) float f32x4;

__device__ inline unsigned short f2bf(float x) {      // RNE f32 -> bf16 bits
    unsigned u = __float_as_uint(x);
    unsigned r = 0x7FFFu + ((u >> 16) & 1u);
    return (unsigned short)((u + r) >> 16);
}
__device__ inline float bf2f(unsigned short h) {
    return __uint_as_float(((unsigned)h) << 16);
}
__device__ inline unsigned pk_trunc(float a, float b) { // 2 f32 -> 2 bf16 (trunc)
    return (__float_as_uint(a) >> 16) | (__float_as_uint(b) & 0xFFFF0000u);
}
__device__ inline float hi_of(float x) {                // bf2f(trunc(x)) in one op
    return __uint_as_float(__float_as_uint(x) & 0xFFFF0000u);
}
// swizzled elem offset into a [rows][32]-short tile; 16B granule slot 0..3
__device__ inline int swz(int row, int slot) {
    return row*32 + (((slot ^ (row >> 1)) & 3) << 3);
}

// ---------------- prep: C -> chunk-major bf16 hi/lo (RNE), c2 in f64 ----------------
__global__ __launch_bounds__(256) void kprep(const float* __restrict__ C,
    short* __restrict__ Chik, short* __restrict__ Clok,
    float* __restrict__ c2f, int* __restrict__ fix_cnt)
{
    const int k = blockIdx.x;      // centroid
    const int t = threadIdx.x;
    __shared__ double red[4];
    double s = 0.0;
    for (int d = t; d < D_DIM; d += 256) {
        float x = C[(size_t)k*D_DIM + d];
        unsigned short h = f2bf(x);
        unsigned short l = f2bf(x - bf2f(h));
        int ch = d >> 5, kk = d & 31;
        size_t o = ((size_t)ch*K_C + k)*KC + kk;
        Chik[o] = (short)h;
        Clok[o] = (short)l;
        s += (double)x * (double)x;
    }
#pragma unroll
    for (int m = 1; m < 64; m <<= 1) s += __shfl_xor(s, m, 64);
    if ((t & 63) == 0) red[t >> 6] = s;
    __syncthreads();
    if (t == 0) {
        c2f[k] = (float)(red[0] + red[1] + red[2] + red[3]);
        if (k == 0) *fix_cnt = 0;
    }
}

// ---------------- main fused MFMA kernel: 128 rows x 256 cols, 8 waves ----------------
__global__ __launch_bounds__(512, 4) void kdist(const float* __restrict__ E,
    const short* __restrict__ Chik, const short* __restrict__ Clok,
    const float* __restrict__ c2f, float* __restrict__ labels,
    float* __restrict__ partials, int* __restrict__ fix_cnt,
    int* __restrict__ fix_list)
{
    __shared__ __align__(16) char ldsbuf[49152];     // 48 KB arena
    short* EhiL = (short*)ldsbuf;                    // [128][32] swizzled, 8 KB
    short* EloL = EhiL + BMR*KC;                     // 8 KB
    short* ChiL = EloL + BMR*KC;                     // [256][32] swizzled, 16 KB
    short* CloL = ChiL + K_C*KC;                     // 16 KB
    // epilogue overlay (valid after post-loop barrier)
    float*  e2s   = (float*)ldsbuf;                  // [128]
    float*  spart = (float*)(ldsbuf + 512);          // [2][256][3]
    float4* topb  = (float4*)(ldsbuf + 512 + 6144);  // [4][128]

    const int t    = threadIdx.x;
    const int lane = t & 63;
    const int w    = t >> 6;
    const int wm   = w >> 2, wq = w & 3;             // row-half / col-quarter
    const int c4   = lane & 15, sgr = lane >> 4;
    const int R0   = blockIdx.x * BMR;

    f32x4 acc[4][4];
#pragma unroll
    for (int m = 0; m < 4; ++m)
#pragma unroll
        for (int n = 0; n < 4; ++n) acc[m][n] = (f32x4){0.f,0.f,0.f,0.f};

    // staging addresses
    const int erow = t >> 2, eseg = t & 3;           // E: 128 rows x 4 segs of 8
    const float* Ep = E + (size_t)(R0 + erow)*D_DIM + eseg*8;
    const int eoff = swz(erow, eseg);
    const int crow = t >> 1, cseg = t & 1;           // C: 256 rows x 2 segs of 16
    const short* Chp = Chik + (size_t)crow*KC + cseg*16;
    const short* Clp = Clok + (size_t)crow*KC + cseg*16;
    const int coff0 = swz(crow, cseg*2);
    const int coff1 = swz(crow, cseg*2 + 1);

    float e2p = 0.f;

    for (int ch = 0; ch < NCH; ++ch) {
        __syncthreads();
        const size_t co = (size_t)ch * K_C * KC;
        s16x8 h0 = *reinterpret_cast<const s16x8*>(Chp + co);
        s16x8 h1 = *reinterpret_cast<const s16x8*>(Chp + co + 8);
        s16x8 l0 = *reinterpret_cast<const s16x8*>(Clp + co);
        s16x8 l1 = *reinterpret_cast<const s16x8*>(Clp + co + 8);

        const float* ep = Ep + ch*KC;
        float4 v0 = *reinterpret_cast<const float4*>(ep);
        float4 v1 = *reinterpret_cast<const float4*>(ep + 4);
        e2p = fmaf(v0.x,v0.x,e2p); e2p = fmaf(v0.y,v0.y,e2p);
        e2p = fmaf(v0.z,v0.z,e2p); e2p = fmaf(v0.w,v0.w,e2p);
        e2p = fmaf(v1.x,v1.x,e2p); e2p = fmaf(v1.y,v1.y,e2p);
        e2p = fmaf(v1.z,v1.z,e2p); e2p = fmaf(v1.w,v1.w,e2p);
        uint4 H, L;
        H.x = pk_trunc(v0.x, v0.y); H.y = pk_trunc(v0.z, v0.w);
        H.z = pk_trunc(v1.x, v1.y); H.w = pk_trunc(v1.z, v1.w);
        L.x = pk_trunc(v0.x - hi_of(v0.x), v0.y - hi_of(v0.y));
        L.y = pk_trunc(v0.z - hi_of(v0.z), v0.w - hi_of(v0.w));
        L.z = pk_trunc(v1.x - hi_of(v1.x), v1.y - hi_of(v1.y));
        L.w = pk_trunc(v1.z - hi_of(v1.z), v1.w - hi_of(v1.w));

        *reinterpret_cast<uint4*>(&EhiL[eoff]) = H;
        *reinterpret_cast<uint4*>(&EloL[eoff]) = L;
        *reinterpret_cast<s16x8*>(&ChiL[coff0]) = h0;
        *reinterpret_cast<s16x8*>(&ChiL[coff1]) = h1;
        *reinterpret_cast<s16x8*>(&CloL[coff0]) = l0;
        *reinterpret_cast<s16x8*>(&CloL[coff1]) = l1;
        __syncthreads();

        // ---- MFMA: acc += (Ehi+Elo)*Chi + Ehi*Clo ----
        s16x8 ah[4], al[4];
#pragma unroll
        for (int m = 0; m < 4; ++m) {
            int r = wm*64 + m*16 + c4;
            int o = swz(r, sgr);
            ah[m] = *reinterpret_cast<const s16x8*>(&EhiL[o]);
            al[m] = *reinterpret_cast<const s16x8*>(&EloL[o]);
        }
#pragma unroll
        for (int n = 0; n < 4; ++n) {
            int cr = wq*64 + n*16 + c4;
            int o = swz(cr, sgr);
            s16x8 bh = *reinterpret_cast<const s16x8*>(&ChiL[o]);
            s16x8 bl = *reinterpret_cast<const s16x8*>(&CloL[o]);
#pragma unroll
            for (int m = 0; m < 4; ++m)
                acc[m][n] = __builtin_amdgcn_mfma_f32_16x16x32_bf16(ah[m], bh, acc[m][n], 0, 0, 0);
#pragma unroll
            for (int m = 0; m < 4; ++m)
                acc[m][n] = __builtin_amdgcn_mfma_f32_16x16x32_bf16(al[m], bh, acc[m][n], 0, 0, 0);
#pragma unroll
            for (int m = 0; m < 4; ++m)
                acc[m][n] = __builtin_amdgcn_mfma_f32_16x16x32_bf16(ah[m], bl, acc[m][n], 0, 0, 0);
        }
    }

    __syncthreads();                 // all LDS frag reads done; overlay becomes valid
    // e2 per row: each row's e2 spread over 4 threads (eseg)
    {
        float es = e2p + __shfl_xor(e2p, 1, 64);
        es += __shfl_xor(es, 2, 64);
        if ((t & 3) == 0) e2s[t >> 2] = es;
    }
    __syncthreads();

    float e2r[4][4];
#pragma unroll
    for (int m = 0; m < 4; ++m)
#pragma unroll
        for (int g = 0; g < 4; ++g)
            e2r[m][g] = e2s[wm*64 + m*16 + sgr*4 + g];
    float c2v[4];
#pragma unroll
    for (int n = 0; n < 4; ++n) c2v[n] = c2f[wq*64 + n*16 + c4];

    // dot -> dist  (C/D: col=lane&15 <-> centroid frag, row=(lane>>4)*4+g <-> E row)
#pragma unroll
    for (int m = 0; m < 4; ++m)
#pragma unroll
        for (int n = 0; n < 4; ++n) {
            f32x4 v = acc[m][n];
#pragma unroll
            for (int g = 0; g < 4; ++g) {
                float d2 = fmaf(-2.f, v[g], e2r[m][g] + c2v[n]);
                v[g] = sqrtf(fmaxf(d2, 0.f));
            }
            acc[m][n] = v;
        }

    // ---- top-2 per row over this wave's 64 cols ----
#pragma unroll
    for (int m = 0; m < 4; ++m)
#pragma unroll
        for (int g = 0; g < 4; ++g) {
            float v1 = FLT_MAX, v2 = FLT_MAX;
            int i1 = 0x7fffffff, i2 = 0x7fffffff;
#pragma unroll
            for (int n = 0; n < 4; ++n) {
                float d = acc[m][n][g];
                int idx = wq*64 + n*16 + c4;
                if (d < v1)      { v2 = v1; i2 = i1; v1 = d; i1 = idx; }
                else if (d < v2) { v2 = d; i2 = idx; }
            }
#pragma unroll
            for (int msk = 1; msk < 16; msk <<= 1) {
                float b1 = __shfl_xor(v1, msk, 64); int bi1 = __shfl_xor(i1, msk, 64);
                float b2 = __shfl_xor(v2, msk, 64); int bi2 = __shfl_xor(i2, msk, 64);
                bool afirst = (v1 < b1) || (v1 == b1 && i1 < bi1);
                float n1, n2; int ni1, ni2;
                if (afirst) {
                    n1 = v1; ni1 = i1;
                    bool s = (v2 < b1) || (v2 == b1 && i2 < bi1);
                    n2 = s ? v2 : b1; ni2 = s ? i2 : bi1;
                } else {
                    n1 = b1; ni1 = bi1;
                    bool s = (b2 < v1) || (b2 == v1 && bi2 < i1);
                    n2 = s ? b2 : v1; ni2 = s ? bi2 : i1;
                }
                v1 = n1; i1 = ni1; v2 = n2; i2 = ni2;
            }
            if (c4 == 0) {
                float4 r; r.x = v1; r.y = (float)i1; r.z = v2; r.w = (float)i2;
                topb[(size_t)wq*BMR + wm*64 + m*16 + sgr*4 + g] = r;
            }
        }

    // ---- per-centroid softmin partials over this wave's 64 rows ----
#pragma unroll
    for (int n = 0; n < 4; ++n) {
        float m0 = FLT_MAX;
#pragma unroll
        for (int m = 0; m < 4; ++m)
#pragma unroll
            for (int g = 0; g < 4; ++g) m0 = fminf(m0, acc[m][n][g]);
        float s1 = 0.f, s2 = 0.f;
#pragma unroll
        for (int m = 0; m < 4; ++m)
#pragma unroll
            for (int g = 0; g < 4; ++g) {
                float d = acc[m][n][g];
                float e = expf(m0 - d);
                s1 += e; s2 = fmaf(d, e, s2);
            }
#pragma unroll
        for (int msk = 16; msk < 64; msk <<= 1) {
            float om = __shfl_xor(m0, msk, 64);
            float oa = __shfl_xor(s1, msk, 64);
            float ob = __shfl_xor(s2, msk, 64);
            float Mn = fminf(m0, om);
            float sa = expf(Mn - m0), sb = expf(Mn - om);
            s1 = s1*sa + oa*sb;
            s2 = s2*sa + ob*sb;
            m0 = Mn;
        }
        if (lane < 16) {
            int cc = wq*64 + n*16 + c4;
            float* p = &spart[((size_t)wm*K_C + cc)*3];
            p[0] = m0; p[1] = s1; p[2] = s2;
        }
    }
    __syncthreads();

    if (t < BMR) {
        // merge top-2 across 4 col-quarters (ascending index ranges)
        float4 a = topb[t];
        float v1 = a.x, v2 = a.z; int i1 = (int)a.y, i2 = (int)a.w;
#pragma unroll
        for (int q = 1; q < 4; ++q) {
            float4 b = topb[(size_t)q*BMR + t];
            if (v1 <= b.x) {
                bool s = (v2 <= b.x);
                v2 = s ? v2 : b.x; i2 = s ? i2 : (int)b.y;
            } else {
                bool s = (b.z <= v1);
                float nv2 = s ? b.z : v1; int ni2 = s ? (int)b.w : i1;
                v1 = b.x; i1 = (int)b.y; v2 = nv2; i2 = ni2;
            }
        }
        int row = R0 + t;
        labels[row] = (float)i1;
        if (v2 - v1 < MARGIN) {
            int slot = atomicAdd(fix_cnt, 1);
            if (slot < MAXFIX) {
                fix_list[slot*3+0] = row;
                fix_list[slot*3+1] = i1;
                fix_list[slot*3+2] = i2;
            }
        }
    }
    if (t < K_C) {
        const float* p0 = &spart[(size_t)t*3];
        const float* p1 = &spart[((size_t)K_C + t)*3];
        float M = p0[0], A = p0[1], Bv = p0[2];
        float om = p1[0], oa = p1[1], ob = p1[2];
        float Mn = fminf(M, om);
        float sa = expf(Mn - M), sb = expf(Mn - om);
        A = A*sa + oa*sb; Bv = Bv*sa + ob*sb;
        float* p = &partials[((size_t)blockIdx.x*K_C + t)*3];
        p[0] = Mn; p[1] = A; p[2] = Bv;
    }
}

// ---------------- f64 exact compare of flagged top-2 ----------------
__global__ __launch_bounds__(256) void krefB(const float* __restrict__ E,
    const float* __restrict__ C, const int* __restrict__ fix_cnt,
    const int* __restrict__ fix_list, float* __restrict__ labels)
{
    int cnt = *fix_cnt; if (cnt > MAXFIX) cnt = MAXFIX;
    int lane = threadIdx.x & 63;
    int wv = (int)((blockIdx.x * blockDim.x + threadIdx.x) >> 6);
    const int NW = (gridDim.x * blockDim.x) >> 6;
    for (int e = wv; e < cnt; e += NW) {
        int row = fix_list[e*3+0], k1 = fix_list[e*3+1], k2 = fix_list[e*3+2];
        double d1 = 0, d2 = 0, q1 = 0, q2 = 0;
        for (int d = lane; d < D_DIM; d += 64) {
            double ed = (double)E[(size_t)row*D_DIM + d];
            double ca = (double)C[(size_t)k1*D_DIM + d];
            double cb = (double)C[(size_t)k2*D_DIM + d];
            d1 += ed*ca; q1 += ca*ca;
            d2 += ed*cb; q2 += cb*cb;
        }
#pragma unroll
        for (int msk = 32; msk; msk >>= 1) {
            d1 += __shfl_down(d1, msk, 64);
            d2 += __shfl_down(d2, msk, 64);
            q1 += __shfl_down(q1, msk, 64);
            q2 += __shfl_down(q2, msk, 64);
        }
        if (lane == 0) {
            double val1 = q1 - 2.0*d1, val2 = q2 - 2.0*d2;   // e2 cancels
            int lab = (val2 < val1 || (val2 == val1 && k2 < k1)) ? k2 : k1;
            labels[row] = (float)lab;
        }
    }
}

// ---------------- per-centroid global combine ----------------
__global__ __launch_bounds__(256) void kcol(const float* __restrict__ partials,
                                            float* __restrict__ colloss, int NB)
{
    __shared__ float Wm[4], Wa[4], Wb[4];
    const int c = blockIdx.x;
    const int t = threadIdx.x;
    float M = FLT_MAX, A = 0.f, Bv = 0.f;
    for (int b = t; b < NB; b += 256) {
        const float* p = &partials[((size_t)b*K_C + c)*3];
        float om = p[0], oa = p[1], ob = p[2];
        float Mn = fminf(M, om);
        float sa = expf(Mn - M), sb = expf(Mn - om);
        A = A*sa + oa*sb; Bv = Bv*sa + ob*sb; M = Mn;
    }
    for (int msk = 1; msk < 64; msk <<= 1) {
        float om = __shfl_xor(M, msk, 64);
        float oa = __shfl_xor(A, msk, 64);
        float ob = __shfl_xor(Bv, msk, 64);
        float Mn = fminf(M, om);
        float sa = expf(Mn - M), sb = expf(Mn - om);
        A = A*sa + oa*sb; Bv = Bv*sa + ob*sb; M = Mn;
    }
    int lane = t & 63, wv = t >> 6;
    if (lane == 0) { Wm[wv] = M; Wa[wv] = A; Wb[wv] = Bv; }
    __syncthreads();
    if (t == 0) {
#pragma unroll
        for (int i = 1; i < 4; ++i) {
            float om = Wm[i], oa = Wa[i], ob = Wb[i];
            float Mn = fminf(M, om);
            float sa = expf(Mn - M), sb = expf(Mn - om);
            A = A*sa + oa*sb; Bv = Bv*sa + ob*sb; M = Mn;
        }
        colloss[c] = Bv / A;
    }
}

// ---------------- final mean over centroids ----------------
__global__ __launch_bounds__(256) void kfinal(const float* __restrict__ colloss,
                                              float* __restrict__ out)
{
    __shared__ float Ws[4];
    int t = threadIdx.x;
    float v = colloss[t];
    for (int msk = 1; msk < 64; msk <<= 1) v += __shfl_xor(v, msk, 64);
    if ((t & 63) == 0) Ws[t >> 6] = v;
    __syncthreads();
    if (t == 0) out[0] = (Ws[0] + Ws[1] + Ws[2] + Ws[3]) / 256.0f;
}

extern "C" void kernel_launch(void* const* d_in, const int* in_sizes, int n_in,
                              void* d_out, int out_size, void* d_ws, size_t ws_size,
                              hipStream_t stream)
{
    const float* E = (const float*)d_in[0];
    const float* C = (const float*)d_in[1];
    float* out = (float*)d_out;

    const int Bn = in_sizes[0] / D_DIM;      // 65536
    const int NB = Bn / BMR;                 // 512

    char* ws = (char*)d_ws;
    float* c2f      = (float*)ws;                                  // 1 KB
    int*   fix_cnt  = (int*)(ws + 1024);
    int*   fix_list = (int*)(ws + 1088);                           // MAXFIX*12
    short* Chik     = (short*)(ws + 1088 + MAXFIX*12);             // 384 KB
    short* Clok     = Chik + (size_t)NCH*K_C*KC;                   // 384 KB
    float* partials = (float*)(Clok + (size_t)NCH*K_C*KC);         // NB*256*3*4
    float* colloss  = partials + (size_t)NB*K_C*3;
    float* labels   = out + 1;

    kprep <<<K_C, 256, 0, stream>>>(C, Chik, Clok, c2f, fix_cnt);
    kdist <<<NB,  512, 0, stream>>>(E, Chik, Clok, c2f, labels, partials,
                                    fix_cnt, fix_list);
    krefB <<<256, 256, 0, stream>>>(E, C, fix_cnt, fix_list, labels);
    kcol  <<<K_C, 256, 0, stream>>>(partials, colloss, NB);
    kfinal<<<1,   256, 0, stream>>>(colloss, out);
}